// Round 5
// baseline (498.498 us; speedup 1.0000x reference)
//
#include <hip/hip_runtime.h>
#include <math.h>

#define EMB 768
#define NH 12
#define HD 64
#define NL 12
#define NV 50257
#define MAXS 1024
#define S_PAST 1023
#define E3 2304
#define E4 3072

// workspace float offsets
#define WS_H    0
#define WS_QKV  768
#define WS_FC   3072
#define WS_PART 6144   // 192 entries * 68 floats

__device__ __forceinline__ void blockReduce2(float& a, float& b, volatile float* ra, volatile float* rb) {
  int lane = threadIdx.x & 63, wid = threadIdx.x >> 6;
#pragma unroll
  for (int o = 32; o > 0; o >>= 1) { a += __shfl_down(a, o); b += __shfl_down(b, o); }
  if (lane == 0) { ra[wid] = a; rb[wid] = b; }
  __syncthreads();
  if (threadIdx.x == 0) {
    ra[0] = ra[0] + ra[1] + ra[2] + ra[3];
    rb[0] = rb[0] + rb[1] + rb[2] + rb[3];
  }
  __syncthreads();
  a = ra[0]; b = rb[0];
}

// blocks 0..2047: bulk KV copy (slot S_PAST overwritten later by attn_kv).
// blocks 2048..2056: embed h + seed layer-0 qkv bias.
__global__ void copy_embed(const float* __restrict__ pk, const float* __restrict__ pv,
                           float* __restrict__ opk, float* __restrict__ opv,
                           const int* __restrict__ ids, const float* __restrict__ wte,
                           const float* __restrict__ wpe, const float* __restrict__ attn_b,
                           float* __restrict__ hvec, float* __restrict__ qkv) {
  int tid = threadIdx.x;
  if (blockIdx.x >= 2048) {
    int bi = blockIdx.x - 2048;                    // 0..8
    qkv[bi * 256 + tid] = attn_b[bi * 256 + tid];
    if (bi < 3) {
      int id = ids[0];
      int e = bi * 256 + tid;
      hvec[e] = wte[(size_t)id * EMB + e] + wpe[(size_t)S_PAST * EMB + e];
    }
    return;
  }
  const size_t n4 = (size_t)NL * NH * MAXS * HD / 4;
  const float4* pk4 = (const float4*)pk;
  const float4* pv4 = (const float4*)pv;
  float4* opk4 = (float4*)opk;
  float4* opv4 = (float4*)opv;
  for (size_t i = (size_t)blockIdx.x * 256 + tid; i < n4; i += (size_t)2048 * 256) {
    opk4[i] = pk4[i];
    opv4[i] = pv4[i];
  }
}

// out[j] += sum_e LN(h)[e] * W[l][e][j]; R rows x 256 cols per block.
template<int R>
__global__ void ln_gemv4(const float* __restrict__ hvec, const float* __restrict__ g,
                         const float* __restrict__ bb, const float* __restrict__ W,
                         float* __restrict__ out, int N, int l) {
  __shared__ float lh[EMB];
  __shared__ float xs[R];
  __shared__ float ra[4], rb[4];
  __shared__ float4 red[4][64];
  int tid = threadIdx.x, lane = tid & 63, wid = tid >> 6;
  float s1 = 0.f, s2 = 0.f;
  for (int e = tid; e < EMB; e += 256) { float v = hvec[e]; lh[e] = v; s1 += v; s2 += v * v; }
  blockReduce2(s1, s2, ra, rb);
  float mean = s1 * (1.f / EMB);
  float var = s2 * (1.f / EMB) - mean * mean;
  float rstd = rsqrtf(var + 1e-5f);
  int e0 = blockIdx.y * R;
  if (tid < R) {
    int e = e0 + tid;
    xs[tid] = (lh[e] - mean) * rstd * g[l * EMB + e] + bb[l * EMB + e];
  }
  __syncthreads();
  int j4 = blockIdx.x * 64 + lane;
  int N4 = N >> 2;
  const float4* p = (const float4*)(W + (size_t)l * EMB * N) + (size_t)e0 * N4 + j4 + (size_t)wid * N4;
  float4 w[R / 4];
#pragma unroll
  for (int i = 0; i < R / 4; i++) w[i] = p[(size_t)(i * 4) * N4];
  float4 acc = {0.f, 0.f, 0.f, 0.f};
#pragma unroll
  for (int i = 0; i < R / 4; i++) {
    float x = xs[wid + i * 4];
    acc.x += x * w[i].x; acc.y += x * w[i].y; acc.z += x * w[i].z; acc.w += x * w[i].w;
  }
  red[wid][lane] = acc;
  __syncthreads();
  if (wid == 0) {
    float4 a0 = red[0][lane], a1 = red[1][lane], a2 = red[2][lane], a3 = red[3][lane];
    float rx = a0.x + a1.x + a2.x + a3.x;
    float ry = a0.y + a1.y + a2.y + a3.y;
    float rz = a0.z + a1.z + a2.z + a3.z;
    float rw = a0.w + a1.w + a2.w + a3.w;
    float* op = out + (size_t)j4 * 4;
    atomicAdd(op + 0, rx); atomicAdd(op + 1, ry);
    atomicAdd(op + 2, rz); atomicAdd(op + 3, rw);
  }
}

// attention partials for one (head, 64-key chunk); chunk 15 also writes new K/V slot
__global__ void attn_kv(const float* __restrict__ qkv, const float* __restrict__ pk,
                        const float* __restrict__ pv, const float* __restrict__ mask,
                        float* __restrict__ opk, float* __restrict__ opv,
                        float* __restrict__ part, int l) {
  int h = blockIdx.x >> 4, c = blockIdx.x & 15;
  int tid = threadIdx.x, lane = tid & 63, wid = tid >> 6;
  int sub = tid & 15, grp = tid >> 4;
  __shared__ float4 qs4[16];
  __shared__ float sc[64];
  __shared__ float4 redo[4][16];
  if (tid < 16) qs4[tid] = ((const float4*)(qkv + h * 64))[tid];
  __syncthreads();
  size_t base = ((size_t)(l * NH + h) * MAXS) * HD;
  const float4* K4 = (const float4*)(pk + base);
  const float4* V4 = (const float4*)(pv + base);
  int t0 = c * 64;
  float4 kreg[4];
#pragma unroll
  for (int i = 0; i < 4; i++) {
    int t = t0 + grp + i * 16;
    kreg[i] = (t == S_PAST) ? ((const float4*)(qkv + EMB + h * 64))[sub] : K4[(size_t)t * 16 + sub];
  }
  if (c == 15 && grp == 15)
    ((float4*)(opk + base))[(size_t)S_PAST * 16 + sub] = kreg[3];
  float4 q4 = qs4[sub];
#pragma unroll
  for (int i = 0; i < 4; i++) {
    int key = grp + i * 16;
    float p = q4.x * kreg[i].x + q4.y * kreg[i].y + q4.z * kreg[i].z + q4.w * kreg[i].w;
    p += __shfl_xor(p, 1); p += __shfl_xor(p, 2);
    p += __shfl_xor(p, 4); p += __shfl_xor(p, 8);
    if (sub == 0) sc[key] = p * 0.125f + (1.f - mask[t0 + key]) * (-1e9f);
  }
  __syncthreads();
  if (wid == 0) {
    float a = sc[lane];
    float m = a;
#pragma unroll
    for (int o = 32; o > 0; o >>= 1) m = fmaxf(m, __shfl_down(m, o));
    m = __shfl(m, 0);
    float ea = expf(a - m);
    sc[lane] = ea;
    float s = ea;
#pragma unroll
    for (int o = 32; o > 0; o >>= 1) s += __shfl_down(s, o);
    if (lane == 0) { part[(h * 16 + c) * 68 + 0] = m; part[(h * 16 + c) * 68 + 1] = s; }
  }
  __syncthreads();
  float4 vreg[4];
#pragma unroll
  for (int i = 0; i < 4; i++) {
    int t = t0 + grp + i * 16;
    vreg[i] = (t == S_PAST) ? ((const float4*)(qkv + 2 * EMB + h * 64))[sub] : V4[(size_t)t * 16 + sub];
  }
  if (c == 15 && grp == 15)
    ((float4*)(opv + base))[(size_t)S_PAST * 16 + sub] = vreg[3];
  float4 acc = {0.f, 0.f, 0.f, 0.f};
#pragma unroll
  for (int i = 0; i < 4; i++) {
    float w = sc[grp + i * 16];
    acc.x += w * vreg[i].x; acc.y += w * vreg[i].y; acc.z += w * vreg[i].z; acc.w += w * vreg[i].w;
  }
  acc.x += __shfl_xor(acc.x, 16); acc.y += __shfl_xor(acc.y, 16);
  acc.z += __shfl_xor(acc.z, 16); acc.w += __shfl_xor(acc.w, 16);
  acc.x += __shfl_xor(acc.x, 32); acc.y += __shfl_xor(acc.y, 32);
  acc.z += __shfl_xor(acc.z, 32); acc.w += __shfl_xor(acc.w, 32);
  if (lane < 16) redo[wid][lane] = acc;
  __syncthreads();
  if (tid < 16) {
    float4 a0 = redo[0][tid], a1 = redo[1][tid], a2 = redo[2][tid], a3 = redo[3][tid];
    float4 r;
    r.x = a0.x + a1.x + a2.x + a3.x;
    r.y = a0.y + a1.y + a2.y + a3.y;
    r.z = a0.z + a1.z + a2.z + a3.z;
    r.w = a0.w + a1.w + a2.w + a3.w;
    ((float4*)(part + (h * 16 + c) * 68 + 4))[tid] = r;
  }
}

// combine 16 chunk-partials (one 16-dim slice of one head), then 16-row GEMV into h
__global__ void proj_attn(const float* __restrict__ part, const float* __restrict__ W,
                          const float* __restrict__ bias, const float* __restrict__ fc_b,
                          float* __restrict__ hout, float* __restrict__ wfc, int l) {
  int jb = blockIdx.x;           // 0..2 col tile
  int rt = blockIdx.y;           // 0..47 row tile (16 rows)
  int h = rt >> 2, esub = rt & 3;
  int tid = threadIdx.x, lane = tid & 63, wid = tid >> 6;
  __shared__ float xs[16];
  __shared__ float4 red[4][64];
  if (tid < 16) {
    float M = -1e30f;
#pragma unroll
    for (int cc = 0; cc < 16; cc++) M = fmaxf(M, part[(h * 16 + cc) * 68]);
    float T = 0.f, o = 0.f;
    int d = esub * 16 + tid;
#pragma unroll
    for (int cc = 0; cc < 16; cc++) {
      float w = expf(part[(h * 16 + cc) * 68] - M);
      T += part[(h * 16 + cc) * 68 + 1] * w;
      o += part[(h * 16 + cc) * 68 + 4 + d] * w;
    }
    xs[tid] = o / T;
  }
  int bid = rt * 3 + jb;
  if (bid < 12) wfc[bid * 256 + tid] = fc_b[l * E4 + bid * 256 + tid];
  __syncthreads();
  int j4 = jb * 64 + lane;
  const int N4 = EMB >> 2;
  int r0 = h * 64 + esub * 16;
  const float4* p = (const float4*)(W + (size_t)l * EMB * EMB) + (size_t)(r0 + wid) * N4 + j4;
  float4 w[4];
#pragma unroll
  for (int i = 0; i < 4; i++) w[i] = p[(size_t)(i * 4) * N4];
  float4 acc = {0.f, 0.f, 0.f, 0.f};
#pragma unroll
  for (int i = 0; i < 4; i++) {
    float x = xs[wid + i * 4];
    acc.x += x * w[i].x; acc.y += x * w[i].y; acc.z += x * w[i].z; acc.w += x * w[i].w;
  }
  red[wid][lane] = acc;
  __syncthreads();
  if (wid == 0) {
    float4 a0 = red[0][lane], a1 = red[1][lane], a2 = red[2][lane], a3 = red[3][lane];
    float rx = a0.x + a1.x + a2.x + a3.x;
    float ry = a0.y + a1.y + a2.y + a3.y;
    float rz = a0.z + a1.z + a2.z + a3.z;
    float rw = a0.w + a1.w + a2.w + a3.w;
    if (rt == 0) {
      const float* bp = bias + l * EMB + jb * 256 + lane * 4;
      rx += bp[0]; ry += bp[1]; rz += bp[2]; rw += bp[3];
    }
    float* op = hout + (size_t)jb * 256 + (size_t)lane * 4;
    atomicAdd(op + 0, rx); atomicAdd(op + 1, ry);
    atomicAdd(op + 2, rz); atomicAdd(op + 3, rw);
  }
}

// h[j] += sum_e gelu(fc[e]) * mlp_w[l][e][j]; 64 rows per block; seed next qkv
__global__ void mlp_gemv4(const float* __restrict__ fcv, const float* __restrict__ W,
                          const float* __restrict__ bias, const float* __restrict__ attn_b,
                          float* __restrict__ hout, float* __restrict__ qkv, int l) {
  __shared__ float xs[64];
  __shared__ float4 red[4][64];
  int tid = threadIdx.x, lane = tid & 63, wid = tid >> 6;
  int e0 = blockIdx.y * 64;
  if (tid < 64) {
    float x = fcv[e0 + tid];
    xs[tid] = 0.5f * x * (1.f + tanhf(0.7978845608028654f * (x + 0.044715f * x * x * x)));
  }
  int bid = blockIdx.y * 3 + blockIdx.x;
  if (l + 1 < NL && bid < 9) qkv[bid * 256 + tid] = attn_b[(l + 1) * E3 + bid * 256 + tid];
  __syncthreads();
  int j4 = blockIdx.x * 64 + lane;
  const int N4 = EMB >> 2;
  const float4* p = (const float4*)(W + (size_t)l * E4 * EMB) + (size_t)(e0 + wid) * N4 + j4;
  float4 w[16];
#pragma unroll
  for (int i = 0; i < 16; i++) w[i] = p[(size_t)(i * 4) * N4];
  float4 acc = {0.f, 0.f, 0.f, 0.f};
#pragma unroll
  for (int i = 0; i < 16; i++) {
    float x = xs[wid + i * 4];
    acc.x += x * w[i].x; acc.y += x * w[i].y; acc.z += x * w[i].z; acc.w += x * w[i].w;
  }
  red[wid][lane] = acc;
  __syncthreads();
  if (wid == 0) {
    float4 a0 = red[0][lane], a1 = red[1][lane], a2 = red[2][lane], a3 = red[3][lane];
    float rx = a0.x + a1.x + a2.x + a3.x;
    float ry = a0.y + a1.y + a2.y + a3.y;
    float rz = a0.z + a1.z + a2.z + a3.z;
    float rw = a0.w + a1.w + a2.w + a3.w;
    if (blockIdx.y == 0) {
      const float* bp = bias + l * EMB + j4 * 4;
      rx += bp[0]; ry += bp[1]; rz += bp[2]; rw += bp[3];
    }
    float* op = hout + (size_t)j4 * 4;
    atomicAdd(op + 0, rx); atomicAdd(op + 1, ry);
    atomicAdd(op + 2, rz); atomicAdd(op + 3, rw);
  }
}

// final LN fused into logits: logits[v] = dot(LN(h), wte[v]); one wave per row
__global__ void logits_lnf(const float* __restrict__ hvec, const float* __restrict__ g,
                           const float* __restrict__ b, const float* __restrict__ wte,
                           float* __restrict__ out) {
  __shared__ float4 xs4[192];
  __shared__ float ra[4], rb[4];
  int tid = threadIdx.x, lane = tid & 63, wid = tid >> 6;
  float s1 = 0.f, s2 = 0.f;
  float v0[3];
  int k = 0;
  for (int e = tid; e < EMB; e += 256, k++) { float v = hvec[e]; v0[k] = v; s1 += v; s2 += v * v; }
  blockReduce2(s1, s2, ra, rb);
  float mean = s1 * (1.f / EMB);
  float var = s2 * (1.f / EMB) - mean * mean;
  float rstd = rsqrtf(var + 1e-5f);
  k = 0;
  for (int e = tid; e < EMB; e += 256, k++)
    ((float*)xs4)[e] = (v0[k] - mean) * rstd * g[e] + b[e];
  __syncthreads();
  int v = blockIdx.x * 4 + wid;
  if (v >= NV) return;
  const float4* row = (const float4*)(wte + (size_t)v * EMB);
  float4 a0 = row[lane], a1 = row[lane + 64], a2 = row[lane + 128];
  float4 x0 = xs4[lane], x1 = xs4[lane + 64], x2 = xs4[lane + 128];
  float acc = a0.x * x0.x + a0.y * x0.y + a0.z * x0.z + a0.w * x0.w
            + a1.x * x1.x + a1.y * x1.y + a1.z * x1.z + a1.w * x1.w
            + a2.x * x2.x + a2.y * x2.y + a2.z * x2.z + a2.w * x2.w;
#pragma unroll
  for (int o = 32; o > 0; o >>= 1) acc += __shfl_down(acc, o);
  if (lane == 0) out[v] = acc;
}

extern "C" void kernel_launch(void* const* d_in, const int* in_sizes, int n_in,
                              void* d_out, int out_size, void* d_ws, size_t ws_size,
                              hipStream_t stream) {
  const int* input_ids = (const int*)d_in[0];
  const float* past_key = (const float*)d_in[1];
  const float* past_value = (const float*)d_in[2];
  const float* mask = (const float*)d_in[4];
  const float* wte = (const float*)d_in[5];
  const float* wpe = (const float*)d_in[6];
  const float* ln1_g = (const float*)d_in[7];
  const float* ln1_b = (const float*)d_in[8];
  const float* attn_w = (const float*)d_in[9];
  const float* attn_b = (const float*)d_in[10];
  const float* proj_w = (const float*)d_in[11];
  const float* proj_b = (const float*)d_in[12];
  const float* ln2_g = (const float*)d_in[13];
  const float* ln2_b = (const float*)d_in[14];
  const float* fc_w = (const float*)d_in[15];
  const float* fc_b = (const float*)d_in[16];
  const float* mlp_w = (const float*)d_in[17];
  const float* mlp_b = (const float*)d_in[18];
  const float* lnf_g = (const float*)d_in[19];
  const float* lnf_b = (const float*)d_in[20];

  float* out = (float*)d_out;
  float* out_logits = out;
  float* out_pk = out + NV;
  float* out_pv = out_pk + (size_t)NL * NH * MAXS * HD;

  float* ws = (float*)d_ws;
  float* wh = ws + WS_H;
  float* wqkv = ws + WS_QKV;
  float* wfc = ws + WS_FC;
  float* wpart = ws + WS_PART;

  copy_embed<<<2057, 256, 0, stream>>>(past_key, past_value, out_pk, out_pv,
                                       input_ids, wte, wpe, attn_b, wh, wqkv);

  for (int l = 0; l < NL; l++) {
    ln_gemv4<32><<<dim3(9, 24), 256, 0, stream>>>(wh, ln1_g, ln1_b, attn_w, wqkv, E3, l);
    attn_kv<<<192, 256, 0, stream>>>(wqkv, past_key, past_value, mask, out_pk, out_pv, wpart, l);
    proj_attn<<<dim3(3, 48), 256, 0, stream>>>(wpart, proj_w, proj_b, fc_b, wh, wfc, l);
    ln_gemv4<32><<<dim3(12, 24), 256, 0, stream>>>(wh, ln2_g, ln2_b, fc_w, wfc, E4, l);
    mlp_gemv4<<<dim3(3, 48), 256, 0, stream>>>(wfc, mlp_w, mlp_b, attn_b, wh, wqkv, l);
  }
  logits_lnf<<<12565, 256, 0, stream>>>(wh, lnf_g, lnf_b, wte, out_logits);
}